// Round 8
// baseline (112.556 us; speedup 1.0000x reference)
//
#include <hip/hip_runtime.h>
#include <hip/hip_bf16.h>

#define BSZ 32
#define CIN 128
#define CD 64
#define HH 64
#define WW 64
#define PLANE (HH * WW)
#define NPIX (BSZ * HH * WW)
#define NB 8
#define BN_EPS 1e-5f

typedef __attribute__((ext_vector_type(8))) short short8v;
typedef __attribute__((ext_vector_type(4))) float f32x4;
typedef __attribute__((ext_vector_type(4))) unsigned int u32x4;

static __device__ __forceinline__ short f2bf(float f) {
    __hip_bfloat16 h = __float2bfloat16(f);
    return __builtin_bit_cast(short, h);
}
// packed bf16 convert: dst.lo16 = bf16(lo), dst.hi16 = bf16(hi) (RNE)
static __device__ __forceinline__ unsigned int cvtpk(float lo, float hi) {
    unsigned int r;
    asm("v_cvt_pk_bf16_f32 %0, %1, %2" : "=v"(r) : "v"(lo), "v"(hi));
    return r;
}

// ---------------------------------------------------------------------------
// K0: prepack all matmul weights into MFMA B-fragment order (bf16) + fold BN.
// Fragment layout (verified round 2): element ((s*4+c)*64+l)*8+e holds
// W[k = s*32 + (l>>4)*8 + e][j = c*16 + (l&15)].
// ---------------------------------------------------------------------------
__global__ __launch_bounds__(256) void k_prep(
    const float* __restrict__ coef, const float* __restrict__ ssp,
    const float* __restrict__ sb, const float* __restrict__ f2w,
    const float* __restrict__ reduce_w, const float* __restrict__ g_w,
    const float* __restrict__ dw_g, const float* __restrict__ dw_beta,
    const float* __restrict__ dw_m, const float* __restrict__ dw_v,
    const float* __restrict__ dw_b, const float* __restrict__ g_g,
    const float* __restrict__ g_beta, const float* __restrict__ g_m,
    const float* __restrict__ g_v, const float* __restrict__ g_b,
    short* __restrict__ W1f, short* __restrict__ W2f,
    short* __restrict__ WRf, short* __restrict__ WGf,
    float* __restrict__ cbuf)
{
    const int idx = blockIdx.x * 256 + threadIdx.x;
    if (idx < 36864) {
        const int e = idx & 7, l = (idx >> 3) & 63, c = (idx >> 9) & 3, s = idx >> 11;
        const int k = s * 32 + ((l >> 4) << 3) + e;
        const int j = (c << 4) + (l & 15);
        float v;
        if (k < 512) {
            const int i = k >> 3, t = k & 7;
            v = coef[(i * 64 + j) * 8 + t] * ssp[i * 64 + j];
        } else {
            v = sb[(k - 512) * 64 + j];
        }
        W1f[idx] = f2bf(v);
    } else if (idx < 45056) {
        const int f = idx - 36864;
        const int e = f & 7, l = (f >> 3) & 63, c = (f >> 9) & 3, s = f >> 11;
        const int k = s * 32 + ((l >> 4) << 3) + e;
        const int j = (c << 4) + (l & 15);
        W2f[f] = f2bf(f2w[j * 64 + k]);
    } else if (idx < 53248) {
        const int f = idx - 45056;
        const int e = f & 7, l = (f >> 3) & 63, c = (f >> 9) & 3, s = f >> 11;
        const int k = s * 32 + ((l >> 4) << 3) + e;
        const int j = (c << 4) + (l & 15);
        WRf[f] = f2bf(reduce_w[j * CIN + k]);
    } else if (idx < 57344) {
        const int f = idx - 53248;
        const int e = f & 7, l = (f >> 3) & 63, c = (f >> 9) & 3, s = f >> 11;
        const int k = s * 32 + ((l >> 4) << 3) + e;
        const int j = (c << 4) + (l & 15);
        WGf[f] = f2bf(g_w[j * 64 + k]);
    } else if (idx < 57600) {
        const int q = (idx - 57344) >> 6, c = idx & 63;
        if (q == 0) cbuf[c] = dw_g[c] * rsqrtf(dw_v[c] + BN_EPS);
        else if (q == 1) {
            float sc = dw_g[c] * rsqrtf(dw_v[c] + BN_EPS);
            cbuf[64 + c] = (dw_b[c] - dw_m[c]) * sc + dw_beta[c];
        } else if (q == 2) cbuf[128 + c] = g_g[c] * rsqrtf(g_v[c] + BN_EPS);
        else {
            float sc = g_g[c] * rsqrtf(g_v[c] + BN_EPS);
            cbuf[192 + c] = (g_b[c] - g_m[c]) * sc + g_beta[c];
        }
    }
}

// ---------------------------------------------------------------------------
// K1: 1x1 conv 128->64 via MFMA. (unchanged from round 3)
// ---------------------------------------------------------------------------
__global__ __launch_bounds__(256) void k_reduce_mfma(
    const float* __restrict__ x, const short* __restrict__ WRf,
    const float* __restrict__ bias, float* __restrict__ out)
{
    __shared__ __align__(16) char smem[34048];
    short* As = (short*)smem;
    float* Osh = (float*)smem;
    const int bid = blockIdx.x;
    const int b = bid >> 5, h0 = (bid & 31) * 2;
    const int tid = threadIdx.x;
    const float* xb = x + (size_t)b * CIN * PLANE + h0 * WW;
#pragma unroll 1
    for (int p = 0; p < 64; ++p) {
        const int idx = tid + (p << 8);
        const int c = idx >> 7, rt = idx & 127;
        const float v = xb[(size_t)c * PLANE + rt];
        const int s = c >> 5, g = (c >> 3) & 3, e = c & 7;
        const int mt = rt >> 4, m = rt & 15;
        As[((mt * 4 + s) * 64 + (((g << 4) | m) ^ (s & 7))) * 8 + e] = f2bf(v);
    }
    __syncthreads();
    const int cw = tid >> 6, l = tid & 63;
    f32x4 acc[8];
#pragma unroll
    for (int i = 0; i < 8; ++i) acc[i] = (f32x4){0.f, 0.f, 0.f, 0.f};
#pragma unroll 1
    for (int s = 0; s < 4; ++s) {
        const short8v bfr = *(const short8v*)&WRf[((s * 4 + cw) * 64 + l) * 8];
        const int lx = l ^ (s & 7);
#pragma unroll
        for (int mt = 0; mt < 8; ++mt) {
            const short8v a = *(const short8v*)&As[((mt * 4 + s) * 64 + lx) * 8];
            acc[mt] = __builtin_amdgcn_mfma_f32_16x16x32_bf16(a, bfr, acc[mt], 0, 0, 0);
        }
    }
    __syncthreads();
    const int j = (cw << 4) + (l & 15);
    const float bj = bias[j];
    const int rb = (l >> 4) << 2;
#pragma unroll
    for (int mt = 0; mt < 8; ++mt)
#pragma unroll
        for (int r = 0; r < 4; ++r)
            Osh[j * 133 + mt * 16 + rb + r] = acc[mt][r] + bj;
    __syncthreads();
    float* ob = out + (size_t)b * CD * PLANE + h0 * WW;
#pragma unroll 1
    for (int p = 0; p < 32; ++p) {
        const int idx = tid + (p << 8);
        const int jj = idx >> 7, rt = idx & 127;
        ob[(size_t)jj * PLANE + rt] = Osh[jj * 133 + rt];
    }
}

// ---------------------------------------------------------------------------
// K2/K5: 7x7 depthwise conv, register-streaming, quarter-plane strips.
// (unchanged from round 6)
// ---------------------------------------------------------------------------
template<bool RESID>
__global__ __launch_bounds__(256) void k_dwconv(
    const float* __restrict__ in, const float* __restrict__ filt,
    const float* __restrict__ sc, const float* __restrict__ shv,
    const float* __restrict__ resid, float* __restrict__ out)
{
    const int bid = blockIdx.x;
    const int b = bid >> 6, c4 = (bid >> 2) & 15, strip = bid & 3;
    const int H0 = strip << 4;
    const int c = c4 * 4 + (threadIdx.x >> 6);
    const int lane = threadIdx.x & 63;
    const size_t pbase = ((size_t)b * CD + c) * PLANE;
    const float* plane = in + pbase;
    const float* wp = filt + c * 49;
    float K[49];
#pragma unroll
    for (int q = 0; q < 49; ++q) K[q] = wp[q];
    const float scl = RESID ? 1.f : sc[c];
    const float shf = shv[c];
    const float* rplane = RESID ? (resid + pbase) : nullptr;
    float* oplane = out + pbase;

    float acc[7] = {0.f, 0.f, 0.f, 0.f, 0.f, 0.f, 0.f};
#pragma unroll
    for (int rr = 0; rr < 22; ++rr) {
        const int ra = H0 + rr - 3;
        float rowv = 0.f;
        if (ra >= 0 && ra < 64) rowv = plane[ra * 64 + lane];
        float sh[7];
        sh[3] = rowv;
#pragma unroll
        for (int d = 1; d <= 3; ++d) {
            float tp = __shfl(rowv, lane + d);
            sh[3 + d] = (lane + d < 64) ? tp : 0.f;
            float tm = __shfl(rowv, lane - d);
            sh[3 - d] = (lane - d >= 0) ? tm : 0.f;
        }
#pragma unroll
        for (int dy = 0; dy < 7; ++dy) {
            const int o = rr - dy;
            if (o >= 0 && o < 16) {
                const int slot = o % 7;
#pragma unroll
                for (int dx = 0; dx < 7; ++dx)
                    acc[slot] = fmaf(sh[dx], K[dy * 7 + dx], acc[slot]);
            }
        }
        const int done = rr - 6;
        if (done >= 0 && done < 16) {
            const int slot = done % 7;
            const int h = H0 + done;
            float val;
            if (RESID) val = acc[slot] + shf + rplane[h * 64 + lane];
            else       val = acc[slot] * scl + shf;
            oplane[h * 64 + lane] = val;
            acc[slot] = 0.f;
        }
    }
}

// ---------------------------------------------------------------------------
// K3: fused KAN + f2 + gate + g-conv + BN via bf16 MFMA, NCHW -> NCHW.
// ROUND 8: round-7 structure with the slot-group-field fix: the g field of
// a fragment slot is 2 bits, ((grp>>1)&3) — round 7 omitted the &3, so
// grp>=8 wrote slot 64..127 => OOB LDS (As1 has 9216 shorts, max written
// index was 9720) => NaN. Fixed in BOTH the silu/v staging and y re-stage.
// 16 tokens/group, two sequential groups/block; LDS 20480 B = 8 blocks/CU.
// ---------------------------------------------------------------------------
__global__ __launch_bounds__(256) void k_kan_fused(
    const float* __restrict__ xd, const short* __restrict__ W1f,
    const short* __restrict__ W2f, const short* __restrict__ WGf,
    const float* __restrict__ kb, const float* __restrict__ f2b,
    const float* __restrict__ gs, const float* __restrict__ gsh,
    float* __restrict__ z)
{
    __shared__ __align__(16) short As1[18 * 64 * 8];  // 18 KB (aliased Ysh/Osh)
    __shared__ __align__(16) short As2[2 * 64 * 8];   //  2 KB (v-frags -> y-frags)
    const int tid = threadIdx.x;
    const int tg0 = blockIdx.x * 32;
    const int bb = tg0 >> 12, pix0 = tg0 & 4095;
    const float* xb = xd + (size_t)bb * CD * PLANE + pix0;
    float* zb = z + (size_t)bb * CD * PLANE + pix0;
    const int tkn = tid & 15;   // token within 16-group
    const int grp = tid >> 4;   // channel quad 0..15
    const int m = tkn;
    const int cw = tid >> 6, l = tid & 63;
    const int j = (cw << 4) + (l & 15);
    const int rb = (l >> 4) << 2;
    const float kbj = kb[j], f2bj = f2b[j];
    const float sj = gs[j], hj = gsh[j];
    const int gfield = (grp >> 1) & 3;            // 2-bit group field (THE FIX)
    const int slot16 = (gfield << 4) | m;         // slot for silu/v/y frags
    const int e0 = (grp & 1) * 4;                 // c&7 base

#pragma unroll 1
    for (int g = 0; g < 2; ++g) {
        const int toff = g * 16;
        // ---- stage: 4 consecutive channels (c = grp*4+p) of token tkn ----
        float vf[4], sf[4];
#pragma unroll
        for (int p = 0; p < 4; ++p) {
            const int c = grp * 4 + p;
            const float v = xb[(size_t)c * PLANE + toff + tkn];
            vf[p] = v;
            sf[p] = v * __builtin_amdgcn_rcpf(1.0f + __expf(-v));

            // closed-form uniform cubic B-spline: interval i0, frac u
            const float tt = (v + 2.2f) * 2.5f;
            const float fi = floorf(tt);
            const int i0 = (int)fi;
            const float u = tt - fi;
            const bool inr = (tt >= 0.0f) && (tt < 11.0f);
            const float u2 = u * u, u3 = u2 * u;
            const float t1 = 1.f - u;
            const float w0 = (1.f / 6.f) * t1 * t1 * t1;
            const float w3 = (1.f / 6.f) * u3;
            const float w1 = fmaf(0.5f, u3, 2.f / 3.f) - u2;
            const float w2 = 1.f - w0 - w1 - w3;
            const unsigned W01 = cvtpk(w0, w1);
            const unsigned W23 = cvtpk(w2, w3);
            // window placement via dword select (conflict-free b128 store)
            const int q0 = i0 - 3;
            int a = q0 >> 1;
            const int bpar = q0 & 1;
            if (!inr) a = 100;
            const unsigned A1c = (W01 >> 16) | (W23 << 16);
            const unsigned C0 = bpar ? (W01 << 16) : W01;
            const unsigned C1 = bpar ? A1c : W23;
            const unsigned C2 = bpar ? (W23 >> 16) : 0u;
            u32x4 D;
            D.x = (a == 0) ? C0 : (a == -1) ? C1 : (a == -2) ? C2 : 0u;
            D.y = (a == 1) ? C0 : (a == 0) ? C1 : (a == -1) ? C2 : 0u;
            D.z = (a == 2) ? C0 : (a == 1) ? C1 : (a == 0) ? C2 : 0u;
            D.w = (a == 3) ? C0 : (a == 2) ? C1 : (a == 1) ? C2 : 0u;

            const int s = c >> 2;   // == grp
            const int phys = ((p << 4) | m) ^ (s & 7);
            *(u32x4*)&As1[(s * 64 + phys) * 8] = D;
        }
        {   // silu (k=512+c) + raw-v (k=c) fragments: one b64 store each
            uint2 sv, vv;
            sv.x = cvtpk(sf[0], sf[1]); sv.y = cvtpk(sf[2], sf[3]);
            vv.x = cvtpk(vf[0], vf[1]); vv.y = cvtpk(vf[2], vf[3]);
            const int s2 = 16 + (grp >> 3);
            *(uint2*)&As1[(s2 * 64 + (slot16 ^ (s2 & 7))) * 8 + e0] = sv;
            const int s3 = grp >> 3;
            *(uint2*)&As2[(s3 * 64 + (slot16 ^ (s3 & 7))) * 8 + e0] = vv;
        }
        __syncthreads();   // B1: staging complete

        // ---- GEMM1 (spline+silu, K=576) and GEMM2 (f2, K=64) ----
        f32x4 accA = {0.f,0.f,0.f,0.f}, accB = {0.f,0.f,0.f,0.f};
#pragma unroll 1
        for (int s = 0; s < 18; ++s) {
            const short8v bfr = *(const short8v*)&W1f[((s * 4 + cw) * 64 + l) * 8];
            const short8v a0 = *(const short8v*)&As1[(s * 64 + (l ^ (s & 7))) * 8];
            accA = __builtin_amdgcn_mfma_f32_16x16x32_bf16(a0, bfr, accA, 0, 0, 0);
        }
#pragma unroll
        for (int s = 0; s < 2; ++s) {
            const short8v bfr = *(const short8v*)&W2f[((s * 4 + cw) * 64 + l) * 8];
            const short8v a0 = *(const short8v*)&As2[(s * 64 + (l ^ s)) * 8];
            accB = __builtin_amdgcn_mfma_f32_16x16x32_bf16(a0, bfr, accB, 0, 0, 0);
        }

        // y = (x1+kb)*(x2+f2b)
        float y0[4];
#pragma unroll
        for (int r = 0; r < 4; ++r)
            y0[r] = (accA[r] + kbj) * (accB[r] + f2bj);
        __syncthreads();   // B2: all As1/As2 GEMM reads done

        // y -> padded f32 Ysh (reuses As1); stride 17 => conflict-free
        float* Ysh = (float*)As1;
#pragma unroll
        for (int r = 0; r < 4; ++r) Ysh[j * 17 + rb + r] = y0[r];
        __syncthreads();   // B3: Ysh complete

        // re-stage y as bf16 A-frags into As2 (coalesced reads + b64 store)
        {
            float yv[4];
#pragma unroll
            for (int p = 0; p < 4; ++p) yv[p] = Ysh[(grp * 4 + p) * 17 + tkn];
            uint2 yy;
            yy.x = cvtpk(yv[0], yv[1]); yy.y = cvtpk(yv[2], yv[3]);
            const int s3 = grp >> 3;
            *(uint2*)&As2[(s3 * 64 + (slot16 ^ (s3 & 7))) * 8 + e0] = yy;
        }
        __syncthreads();   // B4: y-frags complete (Ysh reads done)

        // GEMM3: z = y @ g_w^T (BN folded in epilogue)
        f32x4 acc3 = {0.f,0.f,0.f,0.f};
#pragma unroll
        for (int s = 0; s < 2; ++s) {
            const short8v bfr = *(const short8v*)&WGf[((s * 4 + cw) * 64 + l) * 8];
            const short8v a0 = *(const short8v*)&As2[(s * 64 + (l ^ s)) * 8];
            acc3 = __builtin_amdgcn_mfma_f32_16x16x32_bf16(a0, bfr, acc3, 0, 0, 0);
        }

        float* Osh = (float*)As1;   // safe: past B4, no further Ysh reads
#pragma unroll
        for (int r = 0; r < 4; ++r)
            Osh[j * 17 + rb + r] = acc3[r] * sj + hj;
        __syncthreads();   // B5: Osh complete

        // write z (NCHW, 16 consecutive floats per channel row)
#pragma unroll
        for (int q = 0; q < 4; ++q) {
            const int idx = tid + (q << 8);
            const int jj = idx >> 4, t2 = idx & 15;
            zb[(size_t)jj * PLANE + toff + t2] = Osh[jj * 17 + t2];
        }
        __syncthreads();   // B6: Osh reads done before next group's staging
    }
}

// ---------------------------------------------------------------------------
extern "C" void kernel_launch(void* const* d_in, const int* in_sizes, int n_in,
                              void* d_out, int out_size, void* d_ws, size_t ws_size,
                              hipStream_t stream)
{
    (void)in_sizes; (void)n_in; (void)out_size; (void)ws_size;
    const float* x        = (const float*)d_in[0];
    const float* reduce_w = (const float*)d_in[1];
    const float* reduce_b = (const float*)d_in[2];
    const float* dw_w     = (const float*)d_in[3];
    const float* dw_b     = (const float*)d_in[4];
    const float* dw_g     = (const float*)d_in[5];
    const float* dw_beta  = (const float*)d_in[6];
    const float* dw_m     = (const float*)d_in[7];
    const float* dw_v     = (const float*)d_in[8];
    const float* f2_w     = (const float*)d_in[9];
    const float* f2_b     = (const float*)d_in[10];
    const float* coef     = (const float*)d_in[11];
    const float* sbase    = (const float*)d_in[12];
    const float* ssp      = (const float*)d_in[13];
    const float* kbias    = (const float*)d_in[14];
    const float* g_w      = (const float*)d_in[15];
    const float* g_b      = (const float*)d_in[16];
    const float* g_g      = (const float*)d_in[17];
    const float* g_beta   = (const float*)d_in[18];
    const float* g_m      = (const float*)d_in[19];
    const float* g_v      = (const float*)d_in[20];
    const float* dw2_w    = (const float*)d_in[21];
    const float* dw2_b    = (const float*)d_in[22];
    float* out = (float*)d_out;

    const size_t NEL = (size_t)BSZ * CD * PLANE;
    short* W1f = (short*)d_ws;
    short* W2f = W1f + 36864;
    short* WRf = W2f + 8192;
    short* WGf = WRf + 8192;
    float* cbuf = (float*)((char*)d_ws + 115200);
    float* inp = (float*)((char*)d_ws + 131072);
    float* xdb = inp + NEL;
    float* z   = xdb + NEL;

    k_prep<<<225, 256, 0, stream>>>(coef, ssp, sbase, f2_w, reduce_w, g_w,
                                    dw_g, dw_beta, dw_m, dw_v, dw_b,
                                    g_g, g_beta, g_m, g_v, g_b,
                                    W1f, W2f, WRf, WGf, cbuf);
    k_reduce_mfma<<<BSZ * 32, 256, 0, stream>>>(x, WRf, reduce_b, inp);
    k_dwconv<false><<<BSZ * 16 * 4, 256, 0, stream>>>(inp, dw_w, cbuf, cbuf + 64, nullptr, xdb);
    k_kan_fused<<<NPIX / 32, 256, 0, stream>>>(xdb, W1f, W2f, WGf, kbias, f2_b,
                                               cbuf + 128, cbuf + 192, z);
    k_dwconv<true><<<BSZ * 16 * 4, 256, 0, stream>>>(z, dw2_w, nullptr, dw2_b, inp, out);
}

// Round 9
// 104.969 us; speedup vs baseline: 1.0723x; 1.0723x over previous
//
#include <hip/hip_runtime.h>
#include <hip/hip_bf16.h>

#define BSZ 32
#define CIN 128
#define CD 64
#define HH 64
#define WW 64
#define PLANE (HH * WW)
#define NPIX (BSZ * HH * WW)
#define NB 8
#define BN_EPS 1e-5f

typedef __attribute__((ext_vector_type(8))) short short8v;
typedef __attribute__((ext_vector_type(4))) float f32x4;
typedef __attribute__((ext_vector_type(4))) unsigned int u32x4;

static __device__ __forceinline__ short f2bf(float f) {
    __hip_bfloat16 h = __float2bfloat16(f);
    return __builtin_bit_cast(short, h);
}
// packed bf16 convert: dst.lo16 = bf16(lo), dst.hi16 = bf16(hi) (RNE)
static __device__ __forceinline__ unsigned int cvtpk(float lo, float hi) {
    unsigned int r;
    asm("v_cvt_pk_bf16_f32 %0, %1, %2" : "=v"(r) : "v"(lo), "v"(hi));
    return r;
}

// ---------------------------------------------------------------------------
// K0: prepack all matmul weights into MFMA B-fragment order (bf16) + fold BN.
// Fragment layout (verified round 2): element ((s*4+c)*64+l)*8+e holds
// W[k = s*32 + (l>>4)*8 + e][j = c*16 + (l&15)].
// ---------------------------------------------------------------------------
__global__ __launch_bounds__(256) void k_prep(
    const float* __restrict__ coef, const float* __restrict__ ssp,
    const float* __restrict__ sb, const float* __restrict__ f2w,
    const float* __restrict__ reduce_w, const float* __restrict__ g_w,
    const float* __restrict__ dw_g, const float* __restrict__ dw_beta,
    const float* __restrict__ dw_m, const float* __restrict__ dw_v,
    const float* __restrict__ dw_b, const float* __restrict__ g_g,
    const float* __restrict__ g_beta, const float* __restrict__ g_m,
    const float* __restrict__ g_v, const float* __restrict__ g_b,
    short* __restrict__ W1f, short* __restrict__ W2f,
    short* __restrict__ WRf, short* __restrict__ WGf,
    float* __restrict__ cbuf)
{
    const int idx = blockIdx.x * 256 + threadIdx.x;
    if (idx < 36864) {
        const int e = idx & 7, l = (idx >> 3) & 63, c = (idx >> 9) & 3, s = idx >> 11;
        const int k = s * 32 + ((l >> 4) << 3) + e;
        const int j = (c << 4) + (l & 15);
        float v;
        if (k < 512) {
            const int i = k >> 3, t = k & 7;
            v = coef[(i * 64 + j) * 8 + t] * ssp[i * 64 + j];
        } else {
            v = sb[(k - 512) * 64 + j];
        }
        W1f[idx] = f2bf(v);
    } else if (idx < 45056) {
        const int f = idx - 36864;
        const int e = f & 7, l = (f >> 3) & 63, c = (f >> 9) & 3, s = f >> 11;
        const int k = s * 32 + ((l >> 4) << 3) + e;
        const int j = (c << 4) + (l & 15);
        W2f[f] = f2bf(f2w[j * 64 + k]);
    } else if (idx < 53248) {
        const int f = idx - 45056;
        const int e = f & 7, l = (f >> 3) & 63, c = (f >> 9) & 3, s = f >> 11;
        const int k = s * 32 + ((l >> 4) << 3) + e;
        const int j = (c << 4) + (l & 15);
        WRf[f] = f2bf(reduce_w[j * CIN + k]);
    } else if (idx < 57344) {
        const int f = idx - 53248;
        const int e = f & 7, l = (f >> 3) & 63, c = (f >> 9) & 3, s = f >> 11;
        const int k = s * 32 + ((l >> 4) << 3) + e;
        const int j = (c << 4) + (l & 15);
        WGf[f] = f2bf(g_w[j * 64 + k]);
    } else if (idx < 57600) {
        const int q = (idx - 57344) >> 6, c = idx & 63;
        if (q == 0) cbuf[c] = dw_g[c] * rsqrtf(dw_v[c] + BN_EPS);
        else if (q == 1) {
            float sc = dw_g[c] * rsqrtf(dw_v[c] + BN_EPS);
            cbuf[64 + c] = (dw_b[c] - dw_m[c]) * sc + dw_beta[c];
        } else if (q == 2) cbuf[128 + c] = g_g[c] * rsqrtf(g_v[c] + BN_EPS);
        else {
            float sc = g_g[c] * rsqrtf(g_v[c] + BN_EPS);
            cbuf[192 + c] = (g_b[c] - g_m[c]) * sc + g_beta[c];
        }
    }
}

// ---------------------------------------------------------------------------
// K1: 1x1 conv 128->64 via MFMA. (unchanged from round 3)
// ---------------------------------------------------------------------------
__global__ __launch_bounds__(256) void k_reduce_mfma(
    const float* __restrict__ x, const short* __restrict__ WRf,
    const float* __restrict__ bias, float* __restrict__ out)
{
    __shared__ __align__(16) char smem[34048];
    short* As = (short*)smem;
    float* Osh = (float*)smem;
    const int bid = blockIdx.x;
    const int b = bid >> 5, h0 = (bid & 31) * 2;
    const int tid = threadIdx.x;
    const float* xb = x + (size_t)b * CIN * PLANE + h0 * WW;
#pragma unroll 1
    for (int p = 0; p < 64; ++p) {
        const int idx = tid + (p << 8);
        const int c = idx >> 7, rt = idx & 127;
        const float v = xb[(size_t)c * PLANE + rt];
        const int s = c >> 5, g = (c >> 3) & 3, e = c & 7;
        const int mt = rt >> 4, m = rt & 15;
        As[((mt * 4 + s) * 64 + (((g << 4) | m) ^ (s & 7))) * 8 + e] = f2bf(v);
    }
    __syncthreads();
    const int cw = tid >> 6, l = tid & 63;
    f32x4 acc[8];
#pragma unroll
    for (int i = 0; i < 8; ++i) acc[i] = (f32x4){0.f, 0.f, 0.f, 0.f};
#pragma unroll 1
    for (int s = 0; s < 4; ++s) {
        const short8v bfr = *(const short8v*)&WRf[((s * 4 + cw) * 64 + l) * 8];
        const int lx = l ^ (s & 7);
#pragma unroll
        for (int mt = 0; mt < 8; ++mt) {
            const short8v a = *(const short8v*)&As[((mt * 4 + s) * 64 + lx) * 8];
            acc[mt] = __builtin_amdgcn_mfma_f32_16x16x32_bf16(a, bfr, acc[mt], 0, 0, 0);
        }
    }
    __syncthreads();
    const int j = (cw << 4) + (l & 15);
    const float bj = bias[j];
    const int rb = (l >> 4) << 2;
#pragma unroll
    for (int mt = 0; mt < 8; ++mt)
#pragma unroll
        for (int r = 0; r < 4; ++r)
            Osh[j * 133 + mt * 16 + rb + r] = acc[mt][r] + bj;
    __syncthreads();
    float* ob = out + (size_t)b * CD * PLANE + h0 * WW;
#pragma unroll 1
    for (int p = 0; p < 32; ++p) {
        const int idx = tid + (p << 8);
        const int jj = idx >> 7, rt = idx & 127;
        ob[(size_t)jj * PLANE + rt] = Osh[jj * 133 + rt];
    }
}

// ---------------------------------------------------------------------------
// K2/K5: 7x7 depthwise conv, register-streaming, quarter-plane strips.
// (unchanged from round 6)
// ---------------------------------------------------------------------------
template<bool RESID>
__global__ __launch_bounds__(256) void k_dwconv(
    const float* __restrict__ in, const float* __restrict__ filt,
    const float* __restrict__ sc, const float* __restrict__ shv,
    const float* __restrict__ resid, float* __restrict__ out)
{
    const int bid = blockIdx.x;
    const int b = bid >> 6, c4 = (bid >> 2) & 15, strip = bid & 3;
    const int H0 = strip << 4;
    const int c = c4 * 4 + (threadIdx.x >> 6);
    const int lane = threadIdx.x & 63;
    const size_t pbase = ((size_t)b * CD + c) * PLANE;
    const float* plane = in + pbase;
    const float* wp = filt + c * 49;
    float K[49];
#pragma unroll
    for (int q = 0; q < 49; ++q) K[q] = wp[q];
    const float scl = RESID ? 1.f : sc[c];
    const float shf = shv[c];
    const float* rplane = RESID ? (resid + pbase) : nullptr;
    float* oplane = out + pbase;

    float acc[7] = {0.f, 0.f, 0.f, 0.f, 0.f, 0.f, 0.f};
#pragma unroll
    for (int rr = 0; rr < 22; ++rr) {
        const int ra = H0 + rr - 3;
        float rowv = 0.f;
        if (ra >= 0 && ra < 64) rowv = plane[ra * 64 + lane];
        float sh[7];
        sh[3] = rowv;
#pragma unroll
        for (int d = 1; d <= 3; ++d) {
            float tp = __shfl(rowv, lane + d);
            sh[3 + d] = (lane + d < 64) ? tp : 0.f;
            float tm = __shfl(rowv, lane - d);
            sh[3 - d] = (lane - d >= 0) ? tm : 0.f;
        }
#pragma unroll
        for (int dy = 0; dy < 7; ++dy) {
            const int o = rr - dy;
            if (o >= 0 && o < 16) {
                const int slot = o % 7;
#pragma unroll
                for (int dx = 0; dx < 7; ++dx)
                    acc[slot] = fmaf(sh[dx], K[dy * 7 + dx], acc[slot]);
            }
        }
        const int done = rr - 6;
        if (done >= 0 && done < 16) {
            const int slot = done % 7;
            const int h = H0 + done;
            float val;
            if (RESID) val = acc[slot] + shf + rplane[h * 64 + lane];
            else       val = acc[slot] * scl + shf;
            oplane[h * 64 + lane] = val;
            acc[slot] = 0.f;
        }
    }
}

// ---------------------------------------------------------------------------
// K3: fused KAN + f2 + gate + g-conv + BN via bf16 MFMA, NCHW -> NCHW.
// ROUND 9: round-6 verified inner structure (32-token tiles, 2 M-tiles/wave,
// conflict-measured LDS patterns, 128B z-writes) + the W-fetch fix that
// round 8 isolated: (a) weights REGISTER-RESIDENT per wave (w1r[18]/w2r/wgr,
// loaded once per block; GEMM loops become pure ds_read+MFMA, no global
// loads on the critical path); (b) 2 tiles per block (grid 2048) so W L2
// traffic halves vs round 6; (c) GEMM1 fully unrolled (ds_reads pipeline);
// (d) tile-1 x-inputs prefetched into registers before tile-0's barrier.
// ---------------------------------------------------------------------------
__global__ __launch_bounds__(256) void k_kan_fused(
    const float* __restrict__ xd, const short* __restrict__ W1f,
    const short* __restrict__ W2f, const short* __restrict__ WGf,
    const float* __restrict__ kb, const float* __restrict__ f2b,
    const float* __restrict__ gs, const float* __restrict__ gsh,
    float* __restrict__ z)
{
    __shared__ __align__(16) short As1[2 * 18 * 64 * 8];  // 36 KB (aliased Ysh/Osh)
    __shared__ __align__(16) short As2[2 * 2 * 64 * 8];   //  4 KB (v-frags -> y-frags)
    const int tid = threadIdx.x;
    const int tg0 = blockIdx.x * 64;          // 64 tokens per block (2 tiles)
    const int bb = tg0 >> 12, pix0 = tg0 & 4095;
    const float* xb = xd + (size_t)bb * CD * PLANE + pix0;
    float* zb = z + (size_t)bb * CD * PLANE + pix0;
    const int tkn = tid & 31;
    const int w5 = tid >> 5;
    const int mt = tkn >> 4, m = tkn & 15;
    const int cw = tid >> 6, l = tid & 63;
    const int j = (cw << 4) + (l & 15);
    const int rb = (l >> 4) << 2;
    const float kbj = kb[j], f2bj = f2b[j];
    const float sj = gs[j], hj = gsh[j];

    // ---- weights -> registers, once per block ----
    short8v w1r[18];
#pragma unroll
    for (int s = 0; s < 18; ++s)
        w1r[s] = *(const short8v*)&W1f[((s * 4 + cw) * 64 + l) * 8];
    short8v w2r[2], wgr[2];
#pragma unroll
    for (int s = 0; s < 2; ++s) {
        w2r[s] = *(const short8v*)&W2f[((s * 4 + cw) * 64 + l) * 8];
        wgr[s] = *(const short8v*)&WGf[((s * 4 + cw) * 64 + l) * 8];
    }

    // ---- prologue: load tile-0 inputs ----
    float vcur[8];
#pragma unroll
    for (int p = 0; p < 8; ++p)
        vcur[p] = xb[(size_t)(w5 * 8 + p) * PLANE + tkn];

#pragma unroll 1
    for (int t = 0; t < 2; ++t) {
        const int toff = t * 32;
        // ---- staging: basis + silu from vcur (round-6 verified layout) ----
        float vf[8], sf[8];
#pragma unroll
        for (int p = 0; p < 8; ++p) {
            const float v = vcur[p];
            vf[p] = v;
            sf[p] = v * __builtin_amdgcn_rcpf(1.0f + __expf(-v));

            const float tt = (v + 2.2f) * 2.5f;
            const float fi = floorf(tt);
            const int i0 = (int)fi;
            const float u = tt - fi;
            const bool inr = (tt >= 0.0f) && (tt < 11.0f);
            const float u2 = u * u, u3 = u2 * u;
            const float t1 = 1.f - u;
            const float w0 = (1.f / 6.f) * t1 * t1 * t1;
            const float w3 = (1.f / 6.f) * u3;
            const float w1 = fmaf(0.5f, u3, 2.f / 3.f) - u2;
            const float w2 = 1.f - w0 - w1 - w3;
            const unsigned W01 = cvtpk(w0, w1);
            const unsigned W23 = cvtpk(w2, w3);
            const int q0 = i0 - 3;
            int a = q0 >> 1;
            const int bpar = q0 & 1;
            if (!inr) a = 100;
            const unsigned A1c = (W01 >> 16) | (W23 << 16);
            const unsigned C0 = bpar ? (W01 << 16) : W01;
            const unsigned C1 = bpar ? A1c : W23;
            const unsigned C2 = bpar ? (W23 >> 16) : 0u;
            u32x4 D;
            D.x = (a == 0) ? C0 : (a == -1) ? C1 : (a == -2) ? C2 : 0u;
            D.y = (a == 1) ? C0 : (a == 0) ? C1 : (a == -1) ? C2 : 0u;
            D.z = (a == 2) ? C0 : (a == 1) ? C1 : (a == 0) ? C2 : 0u;
            D.w = (a == 3) ? C0 : (a == 2) ? C1 : (a == 1) ? C2 : 0u;

            const int s = w5 * 2 + (p >> 2);
            const int phys = (((p & 3) << 4) | m) ^ (s & 7);
            *(u32x4*)&As1[((mt * 18 + s) * 64 + phys) * 8] = D;
        }
        {   // silu + raw-v fragments: one b128 store each
            short8v vpk, spk;
#pragma unroll
            for (int q = 0; q < 4; ++q) {
                ((unsigned*)&vpk)[q] = cvtpk(vf[2 * q], vf[2 * q + 1]);
                ((unsigned*)&spk)[q] = cvtpk(sf[2 * q], sf[2 * q + 1]);
            }
            const int slot = ((w5 & 3) << 4) | m;
            const int s2 = 16 + (w5 >> 2);
            *(short8v*)&As1[((mt * 18 + s2) * 64 + (slot ^ (s2 & 7))) * 8] = spk;
            const int s3 = w5 >> 2;
            *(short8v*)&As2[((mt * 2 + s3) * 64 + (slot ^ (s3 & 7))) * 8] = vpk;
        }
        // ---- prefetch next tile's inputs (completes under the GEMMs) ----
        if (t == 0) {
#pragma unroll
            for (int p = 0; p < 8; ++p)
                vcur[p] = xb[(size_t)(w5 * 8 + p) * PLANE + 32 + tkn];
        }
        __syncthreads();   // B1: staging complete

        // ---- GEMM1 (K=576) + GEMM2 (K=64), weights from registers ----
        f32x4 accA0 = {0.f,0.f,0.f,0.f}, accA1 = {0.f,0.f,0.f,0.f};
        f32x4 accB0 = {0.f,0.f,0.f,0.f}, accB1 = {0.f,0.f,0.f,0.f};
#pragma unroll
        for (int s = 0; s < 18; ++s) {
            const short8v a0 = *(const short8v*)&As1[((0 * 18 + s) * 64 + (l ^ (s & 7))) * 8];
            const short8v a1 = *(const short8v*)&As1[((1 * 18 + s) * 64 + (l ^ (s & 7))) * 8];
            accA0 = __builtin_amdgcn_mfma_f32_16x16x32_bf16(a0, w1r[s], accA0, 0, 0, 0);
            accA1 = __builtin_amdgcn_mfma_f32_16x16x32_bf16(a1, w1r[s], accA1, 0, 0, 0);
        }
#pragma unroll
        for (int s = 0; s < 2; ++s) {
            const short8v a0 = *(const short8v*)&As2[((0 * 2 + s) * 64 + (l ^ s)) * 8];
            const short8v a1 = *(const short8v*)&As2[((1 * 2 + s) * 64 + (l ^ s)) * 8];
            accB0 = __builtin_amdgcn_mfma_f32_16x16x32_bf16(a0, w2r[s], accB0, 0, 0, 0);
            accB1 = __builtin_amdgcn_mfma_f32_16x16x32_bf16(a1, w2r[s], accB1, 0, 0, 0);
        }

        // y = (x1+kb)*(x2+f2b)
        float y0[4], y1[4];
#pragma unroll
        for (int r = 0; r < 4; ++r) {
            y0[r] = (accA0[r] + kbj) * (accB0[r] + f2bj);
            y1[r] = (accA1[r] + kbj) * (accB1[r] + f2bj);
        }
        __syncthreads();   // B2: all As1/As2 GEMM reads done

        // y -> padded f32 Ysh (reuses As1); stride 33 => near-conflict-free
        float* Ysh = (float*)As1;
#pragma unroll
        for (int r = 0; r < 4; ++r) {
            Ysh[j * 33 + rb + r]      = y0[r];
            Ysh[j * 33 + 16 + rb + r] = y1[r];
        }
        __syncthreads();   // B3: Ysh complete

        // re-stage y as bf16 A-frags into As2 (coalesced reads + b128 store)
        {
            float yv[8];
#pragma unroll
            for (int p = 0; p < 8; ++p) yv[p] = Ysh[(w5 * 8 + p) * 33 + tkn];
            short8v ypk;
#pragma unroll
            for (int q = 0; q < 4; ++q)
                ((unsigned*)&ypk)[q] = cvtpk(yv[2 * q], yv[2 * q + 1]);
            const int slot = ((w5 & 3) << 4) | m;
            const int s3 = w5 >> 2;
            *(short8v*)&As2[((mt * 2 + s3) * 64 + (slot ^ (s3 & 7))) * 8] = ypk;
        }
        __syncthreads();   // B4: y-frags complete (Ysh reads done)

        // GEMM3: z = y @ g_w^T (BN folded in epilogue)
        f32x4 acc30 = {0.f,0.f,0.f,0.f}, acc31 = {0.f,0.f,0.f,0.f};
#pragma unroll
        for (int s = 0; s < 2; ++s) {
            const short8v a0 = *(const short8v*)&As2[((0 * 2 + s) * 64 + (l ^ s)) * 8];
            const short8v a1 = *(const short8v*)&As2[((1 * 2 + s) * 64 + (l ^ s)) * 8];
            acc30 = __builtin_amdgcn_mfma_f32_16x16x32_bf16(a0, wgr[s], acc30, 0, 0, 0);
            acc31 = __builtin_amdgcn_mfma_f32_16x16x32_bf16(a1, wgr[s], acc31, 0, 0, 0);
        }

        float* Osh = (float*)As1;   // safe: Ysh reads all done before B4
#pragma unroll
        for (int r = 0; r < 4; ++r) {
            Osh[j * 33 + rb + r]      = acc30[r] * sj + hj;
            Osh[j * 33 + 16 + rb + r] = acc31[r] * sj + hj;
        }
        __syncthreads();   // B5: Osh complete
#pragma unroll
        for (int q = 0; q < 8; ++q) {
            const int idx = tid + (q << 8);
            const int jj = idx >> 5, t2 = idx & 31;
            zb[(size_t)jj * PLANE + toff + t2] = Osh[jj * 33 + t2];
        }
        __syncthreads();   // B6: Osh reads done before next tile's staging
    }
}

// ---------------------------------------------------------------------------
extern "C" void kernel_launch(void* const* d_in, const int* in_sizes, int n_in,
                              void* d_out, int out_size, void* d_ws, size_t ws_size,
                              hipStream_t stream)
{
    (void)in_sizes; (void)n_in; (void)out_size; (void)ws_size;
    const float* x        = (const float*)d_in[0];
    const float* reduce_w = (const float*)d_in[1];
    const float* reduce_b = (const float*)d_in[2];
    const float* dw_w     = (const float*)d_in[3];
    const float* dw_b     = (const float*)d_in[4];
    const float* dw_g     = (const float*)d_in[5];
    const float* dw_beta  = (const float*)d_in[6];
    const float* dw_m     = (const float*)d_in[7];
    const float* dw_v     = (const float*)d_in[8];
    const float* f2_w     = (const float*)d_in[9];
    const float* f2_b     = (const float*)d_in[10];
    const float* coef     = (const float*)d_in[11];
    const float* sbase    = (const float*)d_in[12];
    const float* ssp      = (const float*)d_in[13];
    const float* kbias    = (const float*)d_in[14];
    const float* g_w      = (const float*)d_in[15];
    const float* g_b      = (const float*)d_in[16];
    const float* g_g      = (const float*)d_in[17];
    const float* g_beta   = (const float*)d_in[18];
    const float* g_m      = (const float*)d_in[19];
    const float* g_v      = (const float*)d_in[20];
    const float* dw2_w    = (const float*)d_in[21];
    const float* dw2_b    = (const float*)d_in[22];
    float* out = (float*)d_out;

    const size_t NEL = (size_t)BSZ * CD * PLANE;
    short* W1f = (short*)d_ws;
    short* W2f = W1f + 36864;
    short* WRf = W2f + 8192;
    short* WGf = WRf + 8192;
    float* cbuf = (float*)((char*)d_ws + 115200);
    float* inp = (float*)((char*)d_ws + 131072);
    float* xdb = inp + NEL;
    float* z   = xdb + NEL;

    k_prep<<<225, 256, 0, stream>>>(coef, ssp, sbase, f2_w, reduce_w, g_w,
                                    dw_g, dw_beta, dw_m, dw_v, dw_b,
                                    g_g, g_beta, g_m, g_v, g_b,
                                    W1f, W2f, WRf, WGf, cbuf);
    k_reduce_mfma<<<BSZ * 32, 256, 0, stream>>>(x, WRf, reduce_b, inp);
    k_dwconv<false><<<BSZ * 16 * 4, 256, 0, stream>>>(inp, dw_w, cbuf, cbuf + 64, nullptr, xdb);
    k_kan_fused<<<NPIX / 64, 256, 0, stream>>>(xdb, W1f, W2f, WGf, kbias, f2_b,
                                               cbuf + 128, cbuf + 192, z);
    k_dwconv<true><<<BSZ * 16 * 4, 256, 0, stream>>>(z, dw2_w, nullptr, dw2_b, inp, out);
}

// Round 10
// 100.121 us; speedup vs baseline: 1.1242x; 1.0484x over previous
//
#include <hip/hip_runtime.h>
#include <hip/hip_bf16.h>

#define BSZ 32
#define CIN 128
#define CD 64
#define HH 64
#define WW 64
#define PLANE (HH * WW)
#define NPIX (BSZ * HH * WW)
#define NB 8
#define BN_EPS 1e-5f

typedef __attribute__((ext_vector_type(8))) short short8v;
typedef __attribute__((ext_vector_type(4))) float f32x4;
typedef __attribute__((ext_vector_type(4))) unsigned int u32x4;

static __device__ __forceinline__ short f2bf(float f) {
    __hip_bfloat16 h = __float2bfloat16(f);
    return __builtin_bit_cast(short, h);
}
// packed bf16 convert: dst.lo16 = bf16(lo), dst.hi16 = bf16(hi) (RNE)
static __device__ __forceinline__ unsigned int cvtpk(float lo, float hi) {
    unsigned int r;
    asm("v_cvt_pk_bf16_f32 %0, %1, %2" : "=v"(r) : "v"(lo), "v"(hi));
    return r;
}
// closed-form uniform cubic B-spline 8-slot window (4 nonzero bf16 weights),
// placed by dword-select — identical math to rounds 6-9 (verified).
static __device__ __forceinline__ u32x4 basisD(float v) {
    const float tt = (v + 2.2f) * 2.5f;
    const float fi = floorf(tt);
    const int i0 = (int)fi;
    const float u = tt - fi;
    const bool inr = (tt >= 0.0f) && (tt < 11.0f);
    const float u2 = u * u, u3 = u2 * u;
    const float t1 = 1.f - u;
    const float w0 = (1.f / 6.f) * t1 * t1 * t1;
    const float w3 = (1.f / 6.f) * u3;
    const float w1 = fmaf(0.5f, u3, 2.f / 3.f) - u2;
    const float w2 = 1.f - w0 - w1 - w3;
    const unsigned W01 = cvtpk(w0, w1);
    const unsigned W23 = cvtpk(w2, w3);
    const int q0 = i0 - 3;
    int a = q0 >> 1;
    const int bpar = q0 & 1;
    if (!inr) a = 100;
    const unsigned A1c = (W01 >> 16) | (W23 << 16);
    const unsigned C0 = bpar ? (W01 << 16) : W01;
    const unsigned C1 = bpar ? A1c : W23;
    const unsigned C2 = bpar ? (W23 >> 16) : 0u;
    u32x4 D;
    D.x = (a == 0) ? C0 : (a == -1) ? C1 : (a == -2) ? C2 : 0u;
    D.y = (a == 1) ? C0 : (a == 0) ? C1 : (a == -1) ? C2 : 0u;
    D.z = (a == 2) ? C0 : (a == 1) ? C1 : (a == 0) ? C2 : 0u;
    D.w = (a == 3) ? C0 : (a == 2) ? C1 : (a == 1) ? C2 : 0u;
    return D;
}

// ---------------------------------------------------------------------------
// K0: prepack all matmul weights into MFMA B-fragment order (bf16) + fold BN.
// Fragment layout (verified round 2): element ((s*4+c)*64+l)*8+e holds
// W[k = s*32 + (l>>4)*8 + e][j = c*16 + (l&15)].
// ---------------------------------------------------------------------------
__global__ __launch_bounds__(256) void k_prep(
    const float* __restrict__ coef, const float* __restrict__ ssp,
    const float* __restrict__ sb, const float* __restrict__ f2w,
    const float* __restrict__ reduce_w, const float* __restrict__ g_w,
    const float* __restrict__ dw_g, const float* __restrict__ dw_beta,
    const float* __restrict__ dw_m, const float* __restrict__ dw_v,
    const float* __restrict__ dw_b, const float* __restrict__ g_g,
    const float* __restrict__ g_beta, const float* __restrict__ g_m,
    const float* __restrict__ g_v, const float* __restrict__ g_b,
    short* __restrict__ W1f, short* __restrict__ W2f,
    short* __restrict__ WRf, short* __restrict__ WGf,
    float* __restrict__ cbuf)
{
    const int idx = blockIdx.x * 256 + threadIdx.x;
    if (idx < 36864) {
        const int e = idx & 7, l = (idx >> 3) & 63, c = (idx >> 9) & 3, s = idx >> 11;
        const int k = s * 32 + ((l >> 4) << 3) + e;
        const int j = (c << 4) + (l & 15);
        float v;
        if (k < 512) {
            const int i = k >> 3, t = k & 7;
            v = coef[(i * 64 + j) * 8 + t] * ssp[i * 64 + j];
        } else {
            v = sb[(k - 512) * 64 + j];
        }
        W1f[idx] = f2bf(v);
    } else if (idx < 45056) {
        const int f = idx - 36864;
        const int e = f & 7, l = (f >> 3) & 63, c = (f >> 9) & 3, s = f >> 11;
        const int k = s * 32 + ((l >> 4) << 3) + e;
        const int j = (c << 4) + (l & 15);
        W2f[f] = f2bf(f2w[j * 64 + k]);
    } else if (idx < 53248) {
        const int f = idx - 45056;
        const int e = f & 7, l = (f >> 3) & 63, c = (f >> 9) & 3, s = f >> 11;
        const int k = s * 32 + ((l >> 4) << 3) + e;
        const int j = (c << 4) + (l & 15);
        WRf[f] = f2bf(reduce_w[j * CIN + k]);
    } else if (idx < 57344) {
        const int f = idx - 53248;
        const int e = f & 7, l = (f >> 3) & 63, c = (f >> 9) & 3, s = f >> 11;
        const int k = s * 32 + ((l >> 4) << 3) + e;
        const int j = (c << 4) + (l & 15);
        WGf[f] = f2bf(g_w[j * 64 + k]);
    } else if (idx < 57600) {
        const int q = (idx - 57344) >> 6, c = idx & 63;
        if (q == 0) cbuf[c] = dw_g[c] * rsqrtf(dw_v[c] + BN_EPS);
        else if (q == 1) {
            float sc = dw_g[c] * rsqrtf(dw_v[c] + BN_EPS);
            cbuf[64 + c] = (dw_b[c] - dw_m[c]) * sc + dw_beta[c];
        } else if (q == 2) cbuf[128 + c] = g_g[c] * rsqrtf(g_v[c] + BN_EPS);
        else {
            float sc = g_g[c] * rsqrtf(g_v[c] + BN_EPS);
            cbuf[192 + c] = (g_b[c] - g_m[c]) * sc + g_beta[c];
        }
    }
}

// ---------------------------------------------------------------------------
// K1: 1x1 conv 128->64 via MFMA. (unchanged from round 3)
// ---------------------------------------------------------------------------
__global__ __launch_bounds__(256) void k_reduce_mfma(
    const float* __restrict__ x, const short* __restrict__ WRf,
    const float* __restrict__ bias, float* __restrict__ out)
{
    __shared__ __align__(16) char smem[34048];
    short* As = (short*)smem;
    float* Osh = (float*)smem;
    const int bid = blockIdx.x;
    const int b = bid >> 5, h0 = (bid & 31) * 2;
    const int tid = threadIdx.x;
    const float* xb = x + (size_t)b * CIN * PLANE + h0 * WW;
#pragma unroll 1
    for (int p = 0; p < 64; ++p) {
        const int idx = tid + (p << 8);
        const int c = idx >> 7, rt = idx & 127;
        const float v = xb[(size_t)c * PLANE + rt];
        const int s = c >> 5, g = (c >> 3) & 3, e = c & 7;
        const int mt = rt >> 4, m = rt & 15;
        As[((mt * 4 + s) * 64 + (((g << 4) | m) ^ (s & 7))) * 8 + e] = f2bf(v);
    }
    __syncthreads();
    const int cw = tid >> 6, l = tid & 63;
    f32x4 acc[8];
#pragma unroll
    for (int i = 0; i < 8; ++i) acc[i] = (f32x4){0.f, 0.f, 0.f, 0.f};
#pragma unroll 1
    for (int s = 0; s < 4; ++s) {
        const short8v bfr = *(const short8v*)&WRf[((s * 4 + cw) * 64 + l) * 8];
        const int lx = l ^ (s & 7);
#pragma unroll
        for (int mt = 0; mt < 8; ++mt) {
            const short8v a = *(const short8v*)&As[((mt * 4 + s) * 64 + lx) * 8];
            acc[mt] = __builtin_amdgcn_mfma_f32_16x16x32_bf16(a, bfr, acc[mt], 0, 0, 0);
        }
    }
    __syncthreads();
    const int j = (cw << 4) + (l & 15);
    const float bj = bias[j];
    const int rb = (l >> 4) << 2;
#pragma unroll
    for (int mt = 0; mt < 8; ++mt)
#pragma unroll
        for (int r = 0; r < 4; ++r)
            Osh[j * 133 + mt * 16 + rb + r] = acc[mt][r] + bj;
    __syncthreads();
    float* ob = out + (size_t)b * CD * PLANE + h0 * WW;
#pragma unroll 1
    for (int p = 0; p < 32; ++p) {
        const int idx = tid + (p << 8);
        const int jj = idx >> 7, rt = idx & 127;
        ob[(size_t)jj * PLANE + rt] = Osh[jj * 133 + rt];
    }
}

// ---------------------------------------------------------------------------
// K2/K5: 7x7 depthwise conv, register-streaming, quarter-plane strips.
// (unchanged from round 6)
// ---------------------------------------------------------------------------
template<bool RESID>
__global__ __launch_bounds__(256) void k_dwconv(
    const float* __restrict__ in, const float* __restrict__ filt,
    const float* __restrict__ sc, const float* __restrict__ shv,
    const float* __restrict__ resid, float* __restrict__ out)
{
    const int bid = blockIdx.x;
    const int b = bid >> 6, c4 = (bid >> 2) & 15, strip = bid & 3;
    const int H0 = strip << 4;
    const int c = c4 * 4 + (threadIdx.x >> 6);
    const int lane = threadIdx.x & 63;
    const size_t pbase = ((size_t)b * CD + c) * PLANE;
    const float* plane = in + pbase;
    const float* wp = filt + c * 49;
    float K[49];
#pragma unroll
    for (int q = 0; q < 49; ++q) K[q] = wp[q];
    const float scl = RESID ? 1.f : sc[c];
    const float shf = shv[c];
    const float* rplane = RESID ? (resid + pbase) : nullptr;
    float* oplane = out + pbase;

    float acc[7] = {0.f, 0.f, 0.f, 0.f, 0.f, 0.f, 0.f};
#pragma unroll
    for (int rr = 0; rr < 22; ++rr) {
        const int ra = H0 + rr - 3;
        float rowv = 0.f;
        if (ra >= 0 && ra < 64) rowv = plane[ra * 64 + lane];
        float sh[7];
        sh[3] = rowv;
#pragma unroll
        for (int d = 1; d <= 3; ++d) {
            float tp = __shfl(rowv, lane + d);
            sh[3 + d] = (lane + d < 64) ? tp : 0.f;
            float tm = __shfl(rowv, lane - d);
            sh[3 - d] = (lane - d >= 0) ? tm : 0.f;
        }
#pragma unroll
        for (int dy = 0; dy < 7; ++dy) {
            const int o = rr - dy;
            if (o >= 0 && o < 16) {
                const int slot = o % 7;
#pragma unroll
                for (int dx = 0; dx < 7; ++dx)
                    acc[slot] = fmaf(sh[dx], K[dy * 7 + dx], acc[slot]);
            }
        }
        const int done = rr - 6;
        if (done >= 0 && done < 16) {
            const int slot = done % 7;
            const int h = H0 + done;
            float val;
            if (RESID) val = acc[slot] + shf + rplane[h * 64 + lane];
            else       val = acc[slot] * scl + shf;
            oplane[h * 64 + lane] = val;
            acc[slot] = 0.f;
        }
    }
}

// ---------------------------------------------------------------------------
// K3: fused KAN + f2 + gate + g-conv + BN, NCHW -> NCHW.
// ROUND 10: BARRIER-FREE wave-autonomous structure. Three prior variants
// (occ 35/50/18%) all ~44-48us => the 6-barrier serial chain is the limiter.
// Here ONE WAVE owns 32 tokens (2 M-tiles) across ALL 4 j-tiles:
//  * GEMM1 spline A-frags computed IN REGISTERS: lane (hi=l>>4, m=l&15) at
//    K-step s needs exactly the 8-slot window of channel c=4s+hi, token m —
//    which is basisD(v). No LDS, no staging sync for 16 of 20 K-steps.
//  * silu/v/y routed through WAVE-PRIVATE LDS pads ([ch][17] u32 holding
//    (tile0,tile1) bf16 pairs; ~2-way banks = free); wave-lockstep order +
//    lgkmcnt replaces __syncthreads. ZERO barriers in the kernel.
//  * B-frags streamed from L2 per j-tile (traffic ~370MB, overlaps VALU).
// ---------------------------------------------------------------------------
__global__ __launch_bounds__(256) void k_kan_fused(
    const float* __restrict__ xd, const short* __restrict__ W1f,
    const short* __restrict__ W2f, const short* __restrict__ WGf,
    const float* __restrict__ kb, const float* __restrict__ f2b,
    const float* __restrict__ gs, const float* __restrict__ gsh,
    float* __restrict__ z)
{
    __shared__ unsigned svS[4][1088];   // silu pairs; reused for y pairs
    __shared__ unsigned svV[4][1088];   // raw-v pairs
    const int tid = threadIdx.x;
    const int wv = tid >> 6, l = tid & 63;
    const int hi = l >> 4, m = l & 15;
    const int tg0 = blockIdx.x * 128 + wv * 32;
    const int bb = tg0 >> 12, pix0 = tg0 & 4095;
    const float* xb = xd + (size_t)bb * CD * PLANE + pix0;
    float* zb = z + (size_t)bb * CD * PLANE + pix0;
    unsigned* sS = svS[wv];
    unsigned* sV = svV[wv];

    // per-lane j-tile constants
    float kbj[4], f2bj[4], sj[4], hj[4];
#pragma unroll
    for (int jt = 0; jt < 4; ++jt) {
        const int j = jt * 16 + m;
        kbj[jt] = kb[j]; f2bj[jt] = f2b[j]; sj[jt] = gs[j]; hj[jt] = gsh[j];
    }

    // prefetch all 32 inputs (deep vmem queue; hides HBM latency)
    float xv0[16], xv1[16];
#pragma unroll
    for (int s = 0; s < 16; ++s) {
        xv0[s] = xb[(size_t)(4 * s + hi) * PLANE + m];
        xv1[s] = xb[(size_t)(4 * s + hi) * PLANE + 16 + m];
    }

    f32x4 accA0[4], accA1[4];
#pragma unroll
    for (int jt = 0; jt < 4; ++jt) {
        accA0[jt] = (f32x4){0.f, 0.f, 0.f, 0.f};
        accA1[jt] = (f32x4){0.f, 0.f, 0.f, 0.f};
    }

    // ---- GEMM1 spline part: A-frags in registers, stash silu/v pairs ----
#pragma unroll
    for (int s = 0; s < 16; ++s) {
        const int c = 4 * s + hi;
        const float v0 = xv0[s], v1 = xv1[s];
        const float sl0 = v0 * __builtin_amdgcn_rcpf(1.0f + __expf(-v0));
        const float sl1 = v1 * __builtin_amdgcn_rcpf(1.0f + __expf(-v1));
        sS[c * 17 + m] = cvtpk(sl0, sl1);
        sV[c * 17 + m] = cvtpk(v0, v1);
        const short8v a0 = __builtin_bit_cast(short8v, basisD(v0));
        const short8v a1 = __builtin_bit_cast(short8v, basisD(v1));
#pragma unroll
        for (int jt = 0; jt < 4; ++jt) {
            const short8v bfr = *(const short8v*)&W1f[((s * 4 + jt) * 64 + l) * 8];
            accA0[jt] = __builtin_amdgcn_mfma_f32_16x16x32_bf16(a0, bfr, accA0[jt], 0, 0, 0);
            accA1[jt] = __builtin_amdgcn_mfma_f32_16x16x32_bf16(a1, bfr, accA1[jt], 0, 0, 0);
        }
    }

    // ---- GEMM1 silu K-steps (s=16,17): frags from wave-private LDS ----
#pragma unroll
    for (int s2 = 0; s2 < 2; ++s2) {
        unsigned q[8];
#pragma unroll
        for (int e = 0; e < 8; ++e)
            q[e] = sS[(s2 * 32 + 8 * hi + e) * 17 + m];
        short8v f0, f1;
#pragma unroll
        for (int qi = 0; qi < 4; ++qi) {
            ((unsigned*)&f0)[qi] = (q[2 * qi] & 0xffffu) | (q[2 * qi + 1] << 16);
            ((unsigned*)&f1)[qi] = (q[2 * qi] >> 16) | (q[2 * qi + 1] & 0xffff0000u);
        }
#pragma unroll
        for (int jt = 0; jt < 4; ++jt) {
            const short8v bfr = *(const short8v*)&W1f[(((16 + s2) * 4 + jt) * 64 + l) * 8];
            accA0[jt] = __builtin_amdgcn_mfma_f32_16x16x32_bf16(f0, bfr, accA0[jt], 0, 0, 0);
            accA1[jt] = __builtin_amdgcn_mfma_f32_16x16x32_bf16(f1, bfr, accA1[jt], 0, 0, 0);
        }
    }

    // ---- GEMM2: x2 = v @ f2w^T ----
    f32x4 accB0[4], accB1[4];
#pragma unroll
    for (int jt = 0; jt < 4; ++jt) {
        accB0[jt] = (f32x4){0.f, 0.f, 0.f, 0.f};
        accB1[jt] = (f32x4){0.f, 0.f, 0.f, 0.f};
    }
#pragma unroll
    for (int s3 = 0; s3 < 2; ++s3) {
        unsigned q[8];
#pragma unroll
        for (int e = 0; e < 8; ++e)
            q[e] = sV[(s3 * 32 + 8 * hi + e) * 17 + m];
        short8v f0, f1;
#pragma unroll
        for (int qi = 0; qi < 4; ++qi) {
            ((unsigned*)&f0)[qi] = (q[2 * qi] & 0xffffu) | (q[2 * qi + 1] << 16);
            ((unsigned*)&f1)[qi] = (q[2 * qi] >> 16) | (q[2 * qi + 1] & 0xffff0000u);
        }
#pragma unroll
        for (int jt = 0; jt < 4; ++jt) {
            const short8v bfr = *(const short8v*)&W2f[((s3 * 4 + jt) * 64 + l) * 8];
            accB0[jt] = __builtin_amdgcn_mfma_f32_16x16x32_bf16(f0, bfr, accB0[jt], 0, 0, 0);
            accB1[jt] = __builtin_amdgcn_mfma_f32_16x16x32_bf16(f1, bfr, accB1[jt], 0, 0, 0);
        }
    }

    // ---- gate: y = (x1+kb)*(x2+f2b); stash y pairs into sS (silu done) ----
    const int rb = hi * 4;   // C-layout row base: row = (l>>4)*4 + r
#pragma unroll
    for (int jt = 0; jt < 4; ++jt)
#pragma unroll
        for (int r = 0; r < 4; ++r) {
            const float ya = (accA0[jt][r] + kbj[jt]) * (accB0[jt][r] + f2bj[jt]);
            const float yb2 = (accA1[jt][r] + kbj[jt]) * (accB1[jt][r] + f2bj[jt]);
            sS[(jt * 16 + m) * 17 + rb + r] = cvtpk(ya, yb2);
        }

    // ---- GEMM3: z = y @ g_w^T (BN folded) ----
    f32x4 acc30[4], acc31[4];
#pragma unroll
    for (int jt = 0; jt < 4; ++jt) {
        acc30[jt] = (f32x4){0.f, 0.f, 0.f, 0.f};
        acc31[jt] = (f32x4){0.f, 0.f, 0.f, 0.f};
    }
#pragma unroll
    for (int s3 = 0; s3 < 2; ++s3) {
        unsigned q[8];
#pragma unroll
        for (int e = 0; e < 8; ++e)
            q[e] = sS[(s3 * 32 + 8 * hi + e) * 17 + m];
        short8v f0, f1;
#pragma unroll
        for (int qi = 0; qi < 4; ++qi) {
            ((unsigned*)&f0)[qi] = (q[2 * qi] & 0xffffu) | (q[2 * qi + 1] << 16);
            ((unsigned*)&f1)[qi] = (q[2 * qi] >> 16) | (q[2 * qi + 1] & 0xffff0000u);
        }
#pragma unroll
        for (int jt = 0; jt < 4; ++jt) {
            const short8v bfr = *(const short8v*)&WGf[((s3 * 4 + jt) * 64 + l) * 8];
            acc30[jt] = __builtin_amdgcn_mfma_f32_16x16x32_bf16(f0, bfr, acc30[jt], 0, 0, 0);
            acc31[jt] = __builtin_amdgcn_mfma_f32_16x16x32_bf16(f1, bfr, acc31[jt], 0, 0, 0);
        }
    }

    // ---- epilogue: BN + direct NCHW stores (16B contiguous per (jt,mt)) ----
#pragma unroll
    for (int jt = 0; jt < 4; ++jt) {
        const int j = jt * 16 + m;
        f32x4 o0, o1;
#pragma unroll
        for (int r = 0; r < 4; ++r) {
            o0[r] = acc30[jt][r] * sj[jt] + hj[jt];
            o1[r] = acc31[jt][r] * sj[jt] + hj[jt];
        }
        *(f32x4*)&zb[(size_t)j * PLANE + rb] = o0;
        *(f32x4*)&zb[(size_t)j * PLANE + 16 + rb] = o1;
    }
}

// ---------------------------------------------------------------------------
extern "C" void kernel_launch(void* const* d_in, const int* in_sizes, int n_in,
                              void* d_out, int out_size, void* d_ws, size_t ws_size,
                              hipStream_t stream)
{
    (void)in_sizes; (void)n_in; (void)out_size; (void)ws_size;
    const float* x        = (const float*)d_in[0];
    const float* reduce_w = (const float*)d_in[1];
    const float* reduce_b = (const float*)d_in[2];
    const float* dw_w     = (const float*)d_in[3];
    const float* dw_b     = (const float*)d_in[4];
    const float* dw_g     = (const float*)d_in[5];
    const float* dw_beta  = (const float*)d_in[6];
    const float* dw_m     = (const float*)d_in[7];
    const float* dw_v     = (const float*)d_in[8];
    const float* f2_w     = (const float*)d_in[9];
    const float* f2_b     = (const float*)d_in[10];
    const float* coef     = (const float*)d_in[11];
    const float* sbase    = (const float*)d_in[12];
    const float* ssp      = (const float*)d_in[13];
    const float* kbias    = (const float*)d_in[14];
    const float* g_w      = (const float*)d_in[15];
    const float* g_b      = (const float*)d_in[16];
    const float* g_g      = (const float*)d_in[17];
    const float* g_beta   = (const float*)d_in[18];
    const float* g_m      = (const float*)d_in[19];
    const float* g_v      = (const float*)d_in[20];
    const float* dw2_w    = (const float*)d_in[21];
    const float* dw2_b    = (const float*)d_in[22];
    float* out = (float*)d_out;

    const size_t NEL = (size_t)BSZ * CD * PLANE;
    short* W1f = (short*)d_ws;
    short* W2f = W1f + 36864;
    short* WRf = W2f + 8192;
    short* WGf = WRf + 8192;
    float* cbuf = (float*)((char*)d_ws + 115200);
    float* inp = (float*)((char*)d_ws + 131072);
    float* xdb = inp + NEL;
    float* z   = xdb + NEL;

    k_prep<<<225, 256, 0, stream>>>(coef, ssp, sbase, f2_w, reduce_w, g_w,
                                    dw_g, dw_beta, dw_m, dw_v, dw_b,
                                    g_g, g_beta, g_m, g_v, g_b,
                                    W1f, W2f, WRf, WGf, cbuf);
    k_reduce_mfma<<<BSZ * 32, 256, 0, stream>>>(x, WRf, reduce_b, inp);
    k_dwconv<false><<<BSZ * 16 * 4, 256, 0, stream>>>(inp, dw_w, cbuf, cbuf + 64, nullptr, xdb);
    k_kan_fused<<<NPIX / 128, 256, 0, stream>>>(xdb, W1f, W2f, WGf, kbias, f2_b,
                                                cbuf + 128, cbuf + 192, z);
    k_dwconv<true><<<BSZ * 16 * 4, 256, 0, stream>>>(z, dw2_w, nullptr, dw2_b, inp, out);
}